// Round 1
// baseline (1837.638 us; speedup 1.0000x reference)
//
#include <hip/hip_runtime.h>
#include <hip/hip_bf16.h>
#include <math.h>

#define BB 4
#define CC 64
#define HH 64
#define WW 64
#define LL 4096   // HH*WW
#define DI 128    // D_INNER
#define DS 16     // D_STATE

// ---------------------------------------------------------------------------
// K1: axial depthwise convs + residual + biases -> t[b,c,h,w]
// ---------------------------------------------------------------------------
__global__ __launch_bounds__(256) void k1_axial(
    const float* __restrict__ x, const float* __restrict__ dwh_w,
    const float* __restrict__ dwh_b, const float* __restrict__ dww_w,
    const float* __restrict__ dww_b, float* __restrict__ t_out) {
  int idx = blockIdx.x * 256 + threadIdx.x;   // < 4*64*64*64 = 1048576
  int w = idx & 63;
  int h = (idx >> 6) & 63;
  int c = (idx >> 12) & 63;
  float xc_ = x[idx];
  float up = (h > 0)  ? x[idx - 64] : 0.f;
  float dn = (h < 63) ? x[idx + 64] : 0.f;
  float lf = (w > 0)  ? x[idx - 1]  : 0.f;
  float rt = (w < 63) ? x[idx + 1]  : 0.f;
  float th = dwh_w[c*3+0]*up + dwh_w[c*3+1]*xc_ + dwh_w[c*3+2]*dn;
  float tw = dww_w[c*3+0]*lf + dww_w[c*3+1]*xc_ + dww_w[c*3+2]*rt;
  t_out[idx] = xc_ + th + dwh_b[c] + tw + dww_b[c];
}

// ---------------------------------------------------------------------------
// K2: 1x1 conv + BN + ReLU -> seq[b,l,c]; LayerNorm -> hn[b,l,c]
// block = 256 threads (4 waves), 64 pixels per block
// ---------------------------------------------------------------------------
__global__ __launch_bounds__(256) void k2_conv1x1_ln(
    const float* __restrict__ t_in, const float* __restrict__ conv_w,
    const float* __restrict__ conv_b, const float* __restrict__ bn_g,
    const float* __restrict__ bn_b, const float* __restrict__ bn_m,
    const float* __restrict__ bn_v, const float* __restrict__ ln_g,
    const float* __restrict__ ln_b, float* __restrict__ seq,
    float* __restrict__ hn) {
  __shared__ float wsm[64 * 65];
  __shared__ float tsm[64 * 65];
  int tid = threadIdx.x;
  int blk = blockIdx.x;           // 256 blocks
  int b  = blk >> 6;
  int p0 = (blk & 63) << 6;       // 64 pixels
  for (int i = tid; i < 4096; i += 256) {
    int co = i >> 6, ci = i & 63;
    wsm[ci * 65 + co] = conv_w[i];                 // transpose, pad 65
  }
  for (int i = tid; i < 4096; i += 256) {
    int ci = i >> 6, pl = i & 63;
    tsm[pl * 65 + ci] = t_in[((b * 64 + ci) << 12) + p0 + pl];  // coalesced
  }
  __syncthreads();
  int co = tid & 63;
  int pw = tid >> 6;  // 0..3
  float scale = bn_g[co] * rsqrtf(bn_v[co] + 1e-5f);
  float shift = bn_b[co] - bn_m[co] * scale;
  float cb = conv_b[co];
  float lg = ln_g[co], lb = ln_b[co];
  for (int j = 0; j < 16; ++j) {
    int pl = j * 4 + pw;
    float acc = 0.f;
    #pragma unroll
    for (int ci = 0; ci < 64; ++ci)
      acc += wsm[ci * 65 + co] * tsm[pl * 65 + ci];
    float v = (acc + cb) * scale + shift;
    v = fmaxf(v, 0.f);
    int p = p0 + pl;
    seq[((size_t)(b * LL + p) << 6) + co] = v;
    // LayerNorm over 64 channels == one wave
    float sum = v, sq = v * v;
    #pragma unroll
    for (int off = 1; off < 64; off <<= 1) {
      sum += __shfl_xor(sum, off, 64);
      sq  += __shfl_xor(sq,  off, 64);
    }
    float mu  = sum * (1.f / 64.f);
    float var = sq * (1.f / 64.f) - mu * mu;
    float inv = rsqrtf(var + 1e-5f);
    hn[((size_t)(b * LL + p) << 6) + co] = (v - mu) * inv * lg + lb;
  }
}

// ---------------------------------------------------------------------------
// K3: in_proj  xz[b,l,d] = sum_c hn[b,l,c]*W[d,c]; split xm / z
// grid.y = half (0: xm, 1: z); block = 128 threads, 8 tokens per block
// ---------------------------------------------------------------------------
__global__ __launch_bounds__(128) void k3_inproj(
    const float* __restrict__ hn, const float* __restrict__ ipw,
    float* __restrict__ xm, float* __restrict__ z) {
  __shared__ float wsm[64 * 128];   // swizzled [c][ (d+c)&127 ]
  __shared__ float hsm[512];
  int tid = threadIdx.x;
  int half = blockIdx.y;
  int blk = blockIdx.x;             // 2048
  int b  = blk >> 9;
  int l0 = (blk & 511) << 3;
  const float* wsrc = ipw + half * 128 * 64;
  for (int i = tid; i < 8192; i += 128) {
    int dg = i >> 6, c = i & 63;
    wsm[c * 128 + ((dg + c) & 127)] = wsrc[i];
  }
  for (int i = tid; i < 512; i += 128)
    hsm[i] = hn[((size_t)(b * LL + l0) << 6) + i];
  __syncthreads();
  float acc[8] = {0.f,0.f,0.f,0.f,0.f,0.f,0.f,0.f};
  for (int c = 0; c < 64; ++c) {
    float wv = wsm[c * 128 + ((tid + c) & 127)];
    #pragma unroll
    for (int t = 0; t < 8; ++t) acc[t] += wv * hsm[t * 64 + c];
  }
  float* dst = half ? z : xm;
  #pragma unroll
  for (int t = 0; t < 8; ++t)
    dst[((size_t)(b * LL + l0 + t) << 7) + tid] = acc[t];
}

// ---------------------------------------------------------------------------
// K4: causal depthwise conv1d + SiLU -> xc; x_proj -> (dt_raw,Bm,Cm);
//     dt_proj + softplus -> dt.  block = 128 threads, 8 tokens
// ---------------------------------------------------------------------------
__global__ __launch_bounds__(128) void k4_conv_proj(
    const float* __restrict__ xm, const float* __restrict__ convd_w,
    const float* __restrict__ convd_b, const float* __restrict__ xpw,
    const float* __restrict__ dpw, const float* __restrict__ dpb,
    float* __restrict__ xc_g, float* __restrict__ dt_g,
    float* __restrict__ Bm_g, float* __restrict__ Cm_g) {
  __shared__ float xms[11 * 128];
  __shared__ float xcs[8 * 132];
  __shared__ float xpws[128 * 36];
  __shared__ float dbcs[8 * 36];
  int tid = threadIdx.x;
  int blk = blockIdx.x;             // 2048
  int b  = blk >> 9;
  int l0 = (blk & 511) << 3;
  for (int r = 0; r < 11; ++r) {
    int l = l0 - 3 + r;
    xms[r * 128 + tid] = (l >= 0) ? xm[((size_t)(b * LL + l) << 7) + tid] : 0.f;
  }
  for (int i = tid; i < 4608; i += 128) {
    int e = i >> 7, d = i & 127;
    xpws[d * 36 + e] = xpw[i];
  }
  __syncthreads();
  float cw0 = convd_w[tid*4+0], cw1 = convd_w[tid*4+1];
  float cw2 = convd_w[tid*4+2], cw3 = convd_w[tid*4+3];
  float cb = convd_b[tid];
  #pragma unroll
  for (int t = 0; t < 8; ++t) {
    float pre = cb + cw0 * xms[t*128 + tid] + cw1 * xms[(t+1)*128 + tid]
                   + cw2 * xms[(t+2)*128 + tid] + cw3 * xms[(t+3)*128 + tid];
    float v = pre / (1.f + __expf(-pre));   // silu
    xcs[t * 132 + tid] = v;
    xc_g[((size_t)(b * LL + l0 + t) << 7) + tid] = v;
  }
  __syncthreads();
  for (int p = tid; p < 288; p += 128) {
    int t = p / 36, e = p - t * 36;
    float acc = 0.f;
    #pragma unroll
    for (int d = 0; d < 128; ++d)
      acc += xpws[d * 36 + e] * xcs[t * 132 + d];
    dbcs[t * 36 + e] = acc;
  }
  __syncthreads();
  float w0 = dpw[tid*4+0], w1 = dpw[tid*4+1], w2 = dpw[tid*4+2], w3 = dpw[tid*4+3];
  float bb = dpb[tid];
  #pragma unroll
  for (int t = 0; t < 8; ++t) {
    float raw = bb + w0 * dbcs[t*36+0] + w1 * dbcs[t*36+1]
                   + w2 * dbcs[t*36+2] + w3 * dbcs[t*36+3];
    float sp = (raw > 20.f) ? raw : log1pf(__expf(raw));   // softplus
    dt_g[((size_t)(b * LL + l0 + t) << 7) + tid] = sp;
  }
  int tl = tid >> 4, s = tid & 15;
  Bm_g[((size_t)(b * LL + l0 + tl) << 4) + s] = dbcs[tl * 36 + 4 + s];
  Cm_g[((size_t)(b * LL + l0 + tl) << 4) + s] = dbcs[tl * 36 + 20 + s];
}

// ---------------------------------------------------------------------------
// K5: selective scan.  1 wave per (b, 4 d-channels); lane = (d_local, s).
// h = h*exp(dt*A) + dt*B*xc ;  y[d] = sum_s h*C  (16-lane shuffle reduce)
// ---------------------------------------------------------------------------
__global__ __launch_bounds__(64) void k5_scan(
    const float* __restrict__ dt_g, const float* __restrict__ Bm_g,
    const float* __restrict__ Cm_g, const float* __restrict__ xc_g,
    const float* __restrict__ A_log, float* __restrict__ y_g) {
  int blk = blockIdx.x;             // 128
  int b  = blk >> 5;
  int d0 = (blk & 31) << 2;
  int lane = threadIdx.x;           // 0..63
  int s = lane & 15, dl = lane >> 4;
  int d = d0 + dl;
  float A = -__expf(A_log[d * 16 + s]);
  float h = 0.f;
  const float* dt_p = dt_g + ((size_t)b * LL << 7);
  const float* xc_p = xc_g + ((size_t)b * LL << 7);
  const float* Bm_p = Bm_g + ((size_t)b * LL << 4);
  const float* Cm_p = Cm_g + ((size_t)b * LL << 4);
  float* y_p = y_g + ((size_t)b * LL << 7);
  #pragma unroll 4
  for (int l = 0; l < LL; ++l) {
    float dtv = dt_p[(l << 7) + d];
    float xcv = xc_p[(l << 7) + d];
    float Bv  = Bm_p[(l << 4) + s];
    float Cv  = Cm_p[(l << 4) + s];
    float dA  = __expf(dtv * A);
    h = h * dA + dtv * Bv * xcv;
    float pr = h * Cv;
    pr += __shfl_xor(pr, 1, 64);
    pr += __shfl_xor(pr, 2, 64);
    pr += __shfl_xor(pr, 4, 64);
    pr += __shfl_xor(pr, 8, 64);
    if (s == 0) y_p[(l << 7) + d] = pr;
  }
}

// ---------------------------------------------------------------------------
// K6: ys = (y + xc*Dp)*silu(z); out_tok = ys@out_proj^T + seq; write NCHW
// block = 128 threads, 16 tokens
// ---------------------------------------------------------------------------
__global__ __launch_bounds__(128) void k6_out(
    const float* __restrict__ y_g, const float* __restrict__ xc_g,
    const float* __restrict__ z_g, const float* __restrict__ Dp,
    const float* __restrict__ opw, const float* __restrict__ seq,
    float* __restrict__ out) {
  __shared__ float yss[16 * 128];
  __shared__ float wsm[128 * 65];
  __shared__ float outs[16 * 65];
  int tid = threadIdx.x;
  int blk = blockIdx.x;             // 1024
  int b  = blk >> 8;
  int p0 = (blk & 255) << 4;
  for (int i = tid; i < 8192; i += 128) {
    int c = i >> 7, d = i & 127;
    wsm[d * 65 + c] = opw[i];
  }
  float dp = Dp[tid];
  #pragma unroll 4
  for (int t = 0; t < 16; ++t) {
    size_t base = ((size_t)(b * LL + p0 + t) << 7) + tid;
    float zz = z_g[base];
    float sil = zz / (1.f + __expf(-zz));
    yss[t * 128 + tid] = (y_g[base] + xc_g[base] * dp) * sil;
  }
  __syncthreads();
  for (int it = 0; it < 8; ++it) {
    int idx = it * 128 + tid;
    int t = idx >> 6, c = idx & 63;
    float acc = 0.f;
    #pragma unroll
    for (int d = 0; d < 128; ++d)
      acc += yss[t * 128 + d] * wsm[d * 65 + c];
    outs[t * 65 + c] = acc + seq[((size_t)(b * LL + p0 + t) << 6) + c];
  }
  __syncthreads();
  for (int it = 0; it < 8; ++it) {
    int idx = it * 128 + tid;
    int pl = idx & 15, c = idx >> 4;
    out[((size_t)(b * 64 + c) << 12) + p0 + pl] = outs[pl * 65 + c];
  }
}

// ---------------------------------------------------------------------------
extern "C" void kernel_launch(void* const* d_in, const int* in_sizes, int n_in,
                              void* d_out, int out_size, void* d_ws, size_t ws_size,
                              hipStream_t stream) {
  const float* x       = (const float*)d_in[0];
  const float* dwh_w   = (const float*)d_in[1];
  const float* dwh_b   = (const float*)d_in[2];
  const float* dww_w   = (const float*)d_in[3];
  const float* dww_b   = (const float*)d_in[4];
  const float* conv_w  = (const float*)d_in[5];
  const float* conv_b  = (const float*)d_in[6];
  const float* bn_g    = (const float*)d_in[7];
  const float* bn_b    = (const float*)d_in[8];
  const float* bn_m    = (const float*)d_in[9];
  const float* bn_v    = (const float*)d_in[10];
  const float* ln_g    = (const float*)d_in[11];
  const float* ln_b    = (const float*)d_in[12];
  const float* ipw     = (const float*)d_in[13];
  const float* convd_w = (const float*)d_in[14];
  const float* convd_b = (const float*)d_in[15];
  const float* xpw     = (const float*)d_in[16];
  const float* dpw     = (const float*)d_in[17];
  const float* dpb     = (const float*)d_in[18];
  const float* A_log   = (const float*)d_in[19];
  const float* Dp      = (const float*)d_in[20];
  const float* opw     = (const float*)d_in[21];
  float* out = (float*)d_out;

  float* ws = (float*)d_ws;
  const size_t M = 1048576;  // 1M floats
  float* t_buf = ws + 0;          // 1M   (dead after K2)
  float* seq   = ws + M;          // 1M   (live to K6)
  float* hn    = ws + 2 * M;      // 1M   (dead after K3) -> reused for Bm/Cm
  float* Bm    = ws + 2 * M;      // 256K (written K4)
  float* Cm    = ws + 2 * M + 262144;  // 256K
  float* xm    = ws + 3 * M;      // 2M   (dead after K4) -> reused for y
  float* y_buf = ws + 3 * M;      // 2M   (written K5)
  float* z_buf = ws + 5 * M;      // 2M
  float* xc    = ws + 7 * M;      // 2M
  float* dt    = ws + 9 * M;      // 2M   => total 11M floats = 44 MB

  k1_axial<<<4096, 256, 0, stream>>>(x, dwh_w, dwh_b, dww_w, dww_b, t_buf);
  k2_conv1x1_ln<<<256, 256, 0, stream>>>(t_buf, conv_w, conv_b, bn_g, bn_b,
                                         bn_m, bn_v, ln_g, ln_b, seq, hn);
  k3_inproj<<<dim3(2048, 2), 128, 0, stream>>>(hn, ipw, xm, z_buf);
  k4_conv_proj<<<2048, 128, 0, stream>>>(xm, convd_w, convd_b, xpw, dpw, dpb,
                                         xc, dt, Bm, Cm);
  k5_scan<<<128, 64, 0, stream>>>(dt, Bm, Cm, xc, A_log, y_buf);
  k6_out<<<1024, 128, 0, stream>>>(y_buf, xc, z_buf, Dp, opw, seq, out);
}

// Round 2
// 325.036 us; speedup vs baseline: 5.6536x; 5.6536x over previous
//
#include <hip/hip_runtime.h>
#include <hip/hip_bf16.h>
#include <math.h>

#define BB 4
#define CC 64
#define HH 64
#define WW 64
#define LL 4096   // HH*WW
#define DI 128    // D_INNER
#define DS 16     // D_STATE

// ---------------------------------------------------------------------------
// K1: axial depthwise convs + residual + biases -> t[b,c,h,w]
// ---------------------------------------------------------------------------
__global__ __launch_bounds__(256) void k1_axial(
    const float* __restrict__ x, const float* __restrict__ dwh_w,
    const float* __restrict__ dwh_b, const float* __restrict__ dww_w,
    const float* __restrict__ dww_b, float* __restrict__ t_out) {
  int idx = blockIdx.x * 256 + threadIdx.x;   // < 4*64*64*64 = 1048576
  int w = idx & 63;
  int h = (idx >> 6) & 63;
  int c = (idx >> 12) & 63;
  float xc_ = x[idx];
  float up = (h > 0)  ? x[idx - 64] : 0.f;
  float dn = (h < 63) ? x[idx + 64] : 0.f;
  float lf = (w > 0)  ? x[idx - 1]  : 0.f;
  float rt = (w < 63) ? x[idx + 1]  : 0.f;
  float th = dwh_w[c*3+0]*up + dwh_w[c*3+1]*xc_ + dwh_w[c*3+2]*dn;
  float tw = dww_w[c*3+0]*lf + dww_w[c*3+1]*xc_ + dww_w[c*3+2]*rt;
  t_out[idx] = xc_ + th + dwh_b[c] + tw + dww_b[c];
}

// ---------------------------------------------------------------------------
// K2: 1x1 conv + BN + ReLU -> seq[b,l,c]; LayerNorm -> hn[b,l,c]
// ---------------------------------------------------------------------------
__global__ __launch_bounds__(256) void k2_conv1x1_ln(
    const float* __restrict__ t_in, const float* __restrict__ conv_w,
    const float* __restrict__ conv_b, const float* __restrict__ bn_g,
    const float* __restrict__ bn_b, const float* __restrict__ bn_m,
    const float* __restrict__ bn_v, const float* __restrict__ ln_g,
    const float* __restrict__ ln_b, float* __restrict__ seq,
    float* __restrict__ hn) {
  __shared__ float wsm[64 * 65];
  __shared__ float tsm[64 * 65];
  int tid = threadIdx.x;
  int blk = blockIdx.x;           // 256 blocks
  int b  = blk >> 6;
  int p0 = (blk & 63) << 6;       // 64 pixels
  for (int i = tid; i < 4096; i += 256) {
    int co = i >> 6, ci = i & 63;
    wsm[ci * 65 + co] = conv_w[i];                 // transpose, pad 65
  }
  for (int i = tid; i < 4096; i += 256) {
    int ci = i >> 6, pl = i & 63;
    tsm[pl * 65 + ci] = t_in[((b * 64 + ci) << 12) + p0 + pl];  // coalesced
  }
  __syncthreads();
  int co = tid & 63;
  int pw = tid >> 6;  // 0..3
  float scale = bn_g[co] * rsqrtf(bn_v[co] + 1e-5f);
  float shift = bn_b[co] - bn_m[co] * scale;
  float cb = conv_b[co];
  float lg = ln_g[co], lb = ln_b[co];
  for (int j = 0; j < 16; ++j) {
    int pl = j * 4 + pw;
    float acc = 0.f;
    #pragma unroll
    for (int ci = 0; ci < 64; ++ci)
      acc += wsm[ci * 65 + co] * tsm[pl * 65 + ci];
    float v = (acc + cb) * scale + shift;
    v = fmaxf(v, 0.f);
    int p = p0 + pl;
    seq[((size_t)(b * LL + p) << 6) + co] = v;
    float sum = v, sq = v * v;
    #pragma unroll
    for (int off = 1; off < 64; off <<= 1) {
      sum += __shfl_xor(sum, off, 64);
      sq  += __shfl_xor(sq,  off, 64);
    }
    float mu  = sum * (1.f / 64.f);
    float var = sq * (1.f / 64.f) - mu * mu;
    float inv = rsqrtf(var + 1e-5f);
    hn[((size_t)(b * LL + p) << 6) + co] = (v - mu) * inv * lg + lb;
  }
}

// ---------------------------------------------------------------------------
// K3: in_proj  xz[b,l,d] = sum_c hn[b,l,c]*W[d,c]; split xm / z
// ---------------------------------------------------------------------------
__global__ __launch_bounds__(128) void k3_inproj(
    const float* __restrict__ hn, const float* __restrict__ ipw,
    float* __restrict__ xm, float* __restrict__ z) {
  __shared__ float wsm[64 * 128];   // swizzled [c][ (d+c)&127 ]
  __shared__ float hsm[512];
  int tid = threadIdx.x;
  int half = blockIdx.y;
  int blk = blockIdx.x;             // 2048
  int b  = blk >> 9;
  int l0 = (blk & 511) << 3;
  const float* wsrc = ipw + half * 128 * 64;
  for (int i = tid; i < 8192; i += 128) {
    int dg = i >> 6, c = i & 63;
    wsm[c * 128 + ((dg + c) & 127)] = wsrc[i];
  }
  for (int i = tid; i < 512; i += 128)
    hsm[i] = hn[((size_t)(b * LL + l0) << 6) + i];
  __syncthreads();
  float acc[8] = {0.f,0.f,0.f,0.f,0.f,0.f,0.f,0.f};
  for (int c = 0; c < 64; ++c) {
    float wv = wsm[c * 128 + ((tid + c) & 127)];
    #pragma unroll
    for (int t = 0; t < 8; ++t) acc[t] += wv * hsm[t * 64 + c];
  }
  float* dst = half ? z : xm;
  #pragma unroll
  for (int t = 0; t < 8; ++t)
    dst[((size_t)(b * LL + l0 + t) << 7) + tid] = acc[t];
}

// ---------------------------------------------------------------------------
// K4: causal depthwise conv1d + SiLU -> xc; x_proj -> (dt_raw,Bm,Cm);
//     dt_proj + softplus -> dt.
// ---------------------------------------------------------------------------
__global__ __launch_bounds__(128) void k4_conv_proj(
    const float* __restrict__ xm, const float* __restrict__ convd_w,
    const float* __restrict__ convd_b, const float* __restrict__ xpw,
    const float* __restrict__ dpw, const float* __restrict__ dpb,
    float* __restrict__ xc_g, float* __restrict__ dt_g,
    float* __restrict__ Bm_g, float* __restrict__ Cm_g) {
  __shared__ float xms[11 * 128];
  __shared__ float xcs[8 * 132];
  __shared__ float xpws[128 * 36];
  __shared__ float dbcs[8 * 36];
  int tid = threadIdx.x;
  int blk = blockIdx.x;             // 2048
  int b  = blk >> 9;
  int l0 = (blk & 511) << 3;
  for (int r = 0; r < 11; ++r) {
    int l = l0 - 3 + r;
    xms[r * 128 + tid] = (l >= 0) ? xm[((size_t)(b * LL + l) << 7) + tid] : 0.f;
  }
  for (int i = tid; i < 4608; i += 128) {
    int e = i >> 7, d = i & 127;
    xpws[d * 36 + e] = xpw[i];
  }
  __syncthreads();
  float cw0 = convd_w[tid*4+0], cw1 = convd_w[tid*4+1];
  float cw2 = convd_w[tid*4+2], cw3 = convd_w[tid*4+3];
  float cb = convd_b[tid];
  #pragma unroll
  for (int t = 0; t < 8; ++t) {
    float pre = cb + cw0 * xms[t*128 + tid] + cw1 * xms[(t+1)*128 + tid]
                   + cw2 * xms[(t+2)*128 + tid] + cw3 * xms[(t+3)*128 + tid];
    float v = pre / (1.f + __expf(-pre));   // silu
    xcs[t * 132 + tid] = v;
    xc_g[((size_t)(b * LL + l0 + t) << 7) + tid] = v;
  }
  __syncthreads();
  for (int p = tid; p < 288; p += 128) {
    int t = p / 36, e = p - t * 36;
    float acc = 0.f;
    #pragma unroll
    for (int d = 0; d < 128; ++d)
      acc += xpws[d * 36 + e] * xcs[t * 132 + d];
    dbcs[t * 36 + e] = acc;
  }
  __syncthreads();
  float w0 = dpw[tid*4+0], w1 = dpw[tid*4+1], w2 = dpw[tid*4+2], w3 = dpw[tid*4+3];
  float bb = dpb[tid];
  #pragma unroll
  for (int t = 0; t < 8; ++t) {
    float raw = bb + w0 * dbcs[t*36+0] + w1 * dbcs[t*36+1]
                   + w2 * dbcs[t*36+2] + w3 * dbcs[t*36+3];
    float sp = (raw > 20.f) ? raw : log1pf(__expf(raw));   // softplus
    dt_g[((size_t)(b * LL + l0 + t) << 7) + tid] = sp;
  }
  int tl = tid >> 4, s = tid & 15;
  Bm_g[((size_t)(b * LL + l0 + tl) << 4) + s] = dbcs[tl * 36 + 4 + s];
  Cm_g[((size_t)(b * LL + l0 + tl) << 4) + s] = dbcs[tl * 36 + 20 + s];
}

// ---------------------------------------------------------------------------
// K5a: per-chunk local scan (h seeded 0) -> h_end, P = prod(exp(dt*A))
// grid: ((b*64 + c)*32 + dg) = 8192 blocks x 64 thr. lane = (dl, s).
// ---------------------------------------------------------------------------
__global__ __launch_bounds__(64) void k5a_chunk(
    const float* __restrict__ dt_g, const float* __restrict__ Bm_g,
    const float* __restrict__ xc_g, const float* __restrict__ A_log,
    float* __restrict__ h_end, float* __restrict__ Pp) {
  int blk = blockIdx.x;
  int dg = blk & 31;
  int c  = (blk >> 5) & 63;
  int b  = blk >> 11;
  int lane = threadIdx.x;
  int s = lane & 15, dl = lane >> 4;
  int d = (dg << 2) + dl;
  float A = -__expf(A_log[d * 16 + s]);
  const float* dt_p = dt_g + ((size_t)b * LL << 7);
  const float* xc_p = xc_g + ((size_t)b * LL << 7);
  const float* Bm_p = Bm_g + ((size_t)b * LL << 4);
  float h = 0.f, p = 1.f;
  int l0 = c << 6;
  #pragma unroll 4
  for (int i = 0; i < 64; ++i) {
    int l = l0 + i;
    float dtv = dt_p[(l << 7) + d];
    float xcv = xc_p[(l << 7) + d];
    float Bv  = Bm_p[(l << 4) + s];
    float dA  = __expf(dtv * A);
    h = h * dA + dtv * Bv * xcv;
    p *= dA;
  }
  size_t o = ((((size_t)b * 64 + c) * 128 + d) << 4) + s;
  h_end[o] = h;
  Pp[o] = p;
}

// ---------------------------------------------------------------------------
// K5b: carry scan over 64 chunks: h_in[c] = H; H = H*P[c] + h_end[c]
// 128 blocks x 64 thr; lane covers (4d x 16s) contiguous.
// ---------------------------------------------------------------------------
__global__ __launch_bounds__(64) void k5b_carry(
    const float* __restrict__ h_end, const float* __restrict__ Pp,
    float* __restrict__ h_in) {
  int blk = blockIdx.x;   // b*32+dg
  int b = blk >> 5, dg = blk & 31;
  int lane = threadIdx.x;
  size_t base = ((size_t)b * 64) * 2048 + (dg << 6) + lane;
  float H = 0.f;
  for (int c = 0; c < 64; ++c) {
    size_t o = base + (size_t)c * 2048;
    h_in[o] = H;
    H = H * Pp[o] + h_end[o];
  }
}

// ---------------------------------------------------------------------------
// K5c: final scan, h seeded with h_in; y[l,d] = sum_s h*C
// ---------------------------------------------------------------------------
__global__ __launch_bounds__(64) void k5c_scan(
    const float* __restrict__ dt_g, const float* __restrict__ Bm_g,
    const float* __restrict__ Cm_g, const float* __restrict__ xc_g,
    const float* __restrict__ A_log, const float* __restrict__ h_in,
    float* __restrict__ y_g) {
  int blk = blockIdx.x;
  int dg = blk & 31;
  int c  = (blk >> 5) & 63;
  int b  = blk >> 11;
  int lane = threadIdx.x;
  int s = lane & 15, dl = lane >> 4;
  int d = (dg << 2) + dl;
  float A = -__expf(A_log[d * 16 + s]);
  const float* dt_p = dt_g + ((size_t)b * LL << 7);
  const float* xc_p = xc_g + ((size_t)b * LL << 7);
  const float* Bm_p = Bm_g + ((size_t)b * LL << 4);
  const float* Cm_p = Cm_g + ((size_t)b * LL << 4);
  float* y_p = y_g + ((size_t)b * LL << 7);
  float h = h_in[((((size_t)b * 64 + c) * 128 + d) << 4) + s];
  int l0 = c << 6;
  #pragma unroll 4
  for (int i = 0; i < 64; ++i) {
    int l = l0 + i;
    float dtv = dt_p[(l << 7) + d];
    float xcv = xc_p[(l << 7) + d];
    float Bv  = Bm_p[(l << 4) + s];
    float Cv  = Cm_p[(l << 4) + s];
    float dA  = __expf(dtv * A);
    h = h * dA + dtv * Bv * xcv;
    float pr = h * Cv;
    pr += __shfl_xor(pr, 1, 64);
    pr += __shfl_xor(pr, 2, 64);
    pr += __shfl_xor(pr, 4, 64);
    pr += __shfl_xor(pr, 8, 64);
    if (s == 0) y_p[(l << 7) + d] = pr;
  }
}

// ---------------------------------------------------------------------------
// K6: ys = (y + xc*Dp)*silu(z); out_tok = ys@out_proj^T + seq; write NCHW
// ---------------------------------------------------------------------------
__global__ __launch_bounds__(128) void k6_out(
    const float* __restrict__ y_g, const float* __restrict__ xc_g,
    const float* __restrict__ z_g, const float* __restrict__ Dp,
    const float* __restrict__ opw, const float* __restrict__ seq,
    float* __restrict__ out) {
  __shared__ float yss[16 * 128];
  __shared__ float wsm[128 * 65];
  __shared__ float outs[16 * 65];
  int tid = threadIdx.x;
  int blk = blockIdx.x;             // 1024
  int b  = blk >> 8;
  int p0 = (blk & 255) << 4;
  for (int i = tid; i < 8192; i += 128) {
    int c = i >> 7, d = i & 127;
    wsm[d * 65 + c] = opw[i];
  }
  float dp = Dp[tid];
  #pragma unroll 4
  for (int t = 0; t < 16; ++t) {
    size_t base = ((size_t)(b * LL + p0 + t) << 7) + tid;
    float zz = z_g[base];
    float sil = zz / (1.f + __expf(-zz));
    yss[t * 128 + tid] = (y_g[base] + xc_g[base] * dp) * sil;
  }
  __syncthreads();
  for (int it = 0; it < 8; ++it) {
    int idx = it * 128 + tid;
    int t = idx >> 6, c = idx & 63;
    float acc = 0.f;
    #pragma unroll
    for (int d = 0; d < 128; ++d)
      acc += yss[t * 128 + d] * wsm[d * 65 + c];
    outs[t * 65 + c] = acc + seq[((size_t)(b * LL + p0 + t) << 6) + c];
  }
  __syncthreads();
  for (int it = 0; it < 8; ++it) {
    int idx = it * 128 + tid;
    int pl = idx & 15, c = idx >> 4;
    out[((size_t)(b * 64 + c) << 12) + p0 + pl] = outs[pl * 65 + c];
  }
}

// ---------------------------------------------------------------------------
extern "C" void kernel_launch(void* const* d_in, const int* in_sizes, int n_in,
                              void* d_out, int out_size, void* d_ws, size_t ws_size,
                              hipStream_t stream) {
  const float* x       = (const float*)d_in[0];
  const float* dwh_w   = (const float*)d_in[1];
  const float* dwh_b   = (const float*)d_in[2];
  const float* dww_w   = (const float*)d_in[3];
  const float* dww_b   = (const float*)d_in[4];
  const float* conv_w  = (const float*)d_in[5];
  const float* conv_b  = (const float*)d_in[6];
  const float* bn_g    = (const float*)d_in[7];
  const float* bn_b    = (const float*)d_in[8];
  const float* bn_m    = (const float*)d_in[9];
  const float* bn_v    = (const float*)d_in[10];
  const float* ln_g    = (const float*)d_in[11];
  const float* ln_b    = (const float*)d_in[12];
  const float* ipw     = (const float*)d_in[13];
  const float* convd_w = (const float*)d_in[14];
  const float* convd_b = (const float*)d_in[15];
  const float* xpw     = (const float*)d_in[16];
  const float* dpw     = (const float*)d_in[17];
  const float* dpb     = (const float*)d_in[18];
  const float* A_log   = (const float*)d_in[19];
  const float* Dp      = (const float*)d_in[20];
  const float* opw     = (const float*)d_in[21];
  float* out = (float*)d_out;

  float* ws = (float*)d_ws;
  const size_t M = 1048576;  // 1M floats
  float* t_buf = ws + 0;          // 1M  (dead after K2 -> reused h_in/P)
  float* seq   = ws + M;          // 1M  (live to K6)
  float* hn    = ws + 2 * M;      // 1M  (dead after K3 -> Bm/Cm/h_end)
  float* Bm    = ws + 2 * M;                    // 256K floats
  float* Cm    = ws + 2 * M + 262144;           // 256K floats
  float* h_end = ws + 2 * M + 524288;           // 512K floats (hn tail)
  float* xm    = ws + 3 * M;      // 2M  (dead after K4 -> y)
  float* y_buf = ws + 3 * M;      // 2M
  float* z_buf = ws + 5 * M;      // 2M
  float* xc    = ws + 7 * M;      // 2M
  float* dt    = ws + 9 * M;      // 2M   => total 11M floats = 44 MB
  float* h_in  = ws + 0;          // 512K floats (t_buf)
  float* P_buf = ws + 524288;     // 512K floats (t_buf tail)

  k1_axial<<<4096, 256, 0, stream>>>(x, dwh_w, dwh_b, dww_w, dww_b, t_buf);
  k2_conv1x1_ln<<<256, 256, 0, stream>>>(t_buf, conv_w, conv_b, bn_g, bn_b,
                                         bn_m, bn_v, ln_g, ln_b, seq, hn);
  k3_inproj<<<dim3(2048, 2), 128, 0, stream>>>(hn, ipw, xm, z_buf);
  k4_conv_proj<<<2048, 128, 0, stream>>>(xm, convd_w, convd_b, xpw, dpw, dpb,
                                         xc, dt, Bm, Cm);
  k5a_chunk<<<8192, 64, 0, stream>>>(dt, Bm, xc, A_log, h_end, P_buf);
  k5b_carry<<<128, 64, 0, stream>>>(h_end, P_buf, h_in);
  k5c_scan<<<8192, 64, 0, stream>>>(dt, Bm, Cm, xc, A_log, h_in, y_buf);
  k6_out<<<1024, 128, 0, stream>>>(y_buf, xc, z_buf, Dp, opw, seq, out);
}

// Round 3
// 265.078 us; speedup vs baseline: 6.9324x; 1.2262x over previous
//
#include <hip/hip_runtime.h>
#include <hip/hip_bf16.h>
#include <math.h>

#define BB 4
#define CC 64
#define HH 64
#define WW 64
#define LL 4096   // HH*WW
#define DI 128    // D_INNER
#define DS 16     // D_STATE

// ---------------------------------------------------------------------------
// K1: axial depthwise convs + residual + biases -> t[b,c,h,w]
// ---------------------------------------------------------------------------
__global__ __launch_bounds__(256) void k1_axial(
    const float* __restrict__ x, const float* __restrict__ dwh_w,
    const float* __restrict__ dwh_b, const float* __restrict__ dww_w,
    const float* __restrict__ dww_b, float* __restrict__ t_out) {
  int idx = blockIdx.x * 256 + threadIdx.x;   // < 4*64*64*64 = 1048576
  int w = idx & 63;
  int h = (idx >> 6) & 63;
  int c = (idx >> 12) & 63;
  float xc_ = x[idx];
  float up = (h > 0)  ? x[idx - 64] : 0.f;
  float dn = (h < 63) ? x[idx + 64] : 0.f;
  float lf = (w > 0)  ? x[idx - 1]  : 0.f;
  float rt = (w < 63) ? x[idx + 1]  : 0.f;
  float th = dwh_w[c*3+0]*up + dwh_w[c*3+1]*xc_ + dwh_w[c*3+2]*dn;
  float tw = dww_w[c*3+0]*lf + dww_w[c*3+1]*xc_ + dww_w[c*3+2]*rt;
  t_out[idx] = xc_ + th + dwh_b[c] + tw + dww_b[c];
}

// ---------------------------------------------------------------------------
// K2: 1x1 conv + BN + ReLU -> seq[b,l,c]; LayerNorm -> hn[b,l,c]
// ---------------------------------------------------------------------------
__global__ __launch_bounds__(256) void k2_conv1x1_ln(
    const float* __restrict__ t_in, const float* __restrict__ conv_w,
    const float* __restrict__ conv_b, const float* __restrict__ bn_g,
    const float* __restrict__ bn_b, const float* __restrict__ bn_m,
    const float* __restrict__ bn_v, const float* __restrict__ ln_g,
    const float* __restrict__ ln_b, float* __restrict__ seq,
    float* __restrict__ hn) {
  __shared__ float wsm[64 * 65];
  __shared__ float tsm[64 * 65];
  int tid = threadIdx.x;
  int blk = blockIdx.x;           // 256 blocks
  int b  = blk >> 6;
  int p0 = (blk & 63) << 6;       // 64 pixels
  for (int i = tid; i < 4096; i += 256) {
    int co = i >> 6, ci = i & 63;
    wsm[ci * 65 + co] = conv_w[i];                 // transpose, pad 65
  }
  for (int i = tid; i < 4096; i += 256) {
    int ci = i >> 6, pl = i & 63;
    tsm[pl * 65 + ci] = t_in[((b * 64 + ci) << 12) + p0 + pl];  // coalesced
  }
  __syncthreads();
  int co = tid & 63;
  int pw = tid >> 6;  // 0..3
  float scale = bn_g[co] * rsqrtf(bn_v[co] + 1e-5f);
  float shift = bn_b[co] - bn_m[co] * scale;
  float cb = conv_b[co];
  float lg = ln_g[co], lb = ln_b[co];
  for (int j = 0; j < 16; ++j) {
    int pl = j * 4 + pw;
    float acc = 0.f;
    #pragma unroll
    for (int ci = 0; ci < 64; ++ci)
      acc += wsm[ci * 65 + co] * tsm[pl * 65 + ci];
    float v = (acc + cb) * scale + shift;
    v = fmaxf(v, 0.f);
    int p = p0 + pl;
    seq[((size_t)(b * LL + p) << 6) + co] = v;
    float sum = v, sq = v * v;
    #pragma unroll
    for (int off = 1; off < 64; off <<= 1) {
      sum += __shfl_xor(sum, off, 64);
      sq  += __shfl_xor(sq,  off, 64);
    }
    float mu  = sum * (1.f / 64.f);
    float var = sq * (1.f / 64.f) - mu * mu;
    float inv = rsqrtf(var + 1e-5f);
    hn[((size_t)(b * LL + p) << 6) + co] = (v - mu) * inv * lg + lb;
  }
}

// ---------------------------------------------------------------------------
// K3: in_proj, register-blocked. 64-token tile, 256 thr, grid.y = half.
// Thread owns 4d x 8t accumulator; inner loop: 3x ds_read_b128 per 32 FMA.
// ---------------------------------------------------------------------------
__global__ __launch_bounds__(256) void k3_inproj(
    const float* __restrict__ hn, const float* __restrict__ ipw,
    float* __restrict__ xm, float* __restrict__ z) {
  __shared__ __align__(16) float wsm[64 * 132];   // [c][d], pad 132
  __shared__ __align__(16) float hsm[64 * 68];    // [c][t], pad 68
  int tid = threadIdx.x;
  int half = blockIdx.y;
  int blk = blockIdx.x;             // 256
  int b  = blk >> 6;
  int l0 = (blk & 63) << 6;         // 64 tokens
  const float* wsrc = ipw + half * 8192;   // [128 d][64 c]
  for (int i = tid; i < 8192; i += 256) {
    int d = i >> 6, c = i & 63;
    wsm[c * 132 + d] = wsrc[i];
  }
  for (int i = tid; i < 4096; i += 256) {
    int t = i >> 6, c = i & 63;
    hsm[c * 68 + t] = hn[((size_t)(b * LL + l0) << 6) + i];
  }
  __syncthreads();
  int d0 = (tid & 31) << 2;   // 0..124
  int t0 = (tid >> 5) << 3;   // 0..56
  float acc[4][8] = {};
  #pragma unroll 8
  for (int c = 0; c < 64; ++c) {
    const float4 w4 = *(const float4*)&wsm[c * 132 + d0];
    const float4 h0 = *(const float4*)&hsm[c * 68 + t0];
    const float4 h1 = *(const float4*)&hsm[c * 68 + t0 + 4];
    const float wv[4] = {w4.x, w4.y, w4.z, w4.w};
    const float hv[8] = {h0.x, h0.y, h0.z, h0.w, h1.x, h1.y, h1.z, h1.w};
    #pragma unroll
    for (int i = 0; i < 4; ++i)
      #pragma unroll
      for (int j = 0; j < 8; ++j)
        acc[i][j] = fmaf(wv[i], hv[j], acc[i][j]);
  }
  float* dst = half ? z : xm;
  #pragma unroll
  for (int j = 0; j < 8; ++j) {
    float4 v = make_float4(acc[0][j], acc[1][j], acc[2][j], acc[3][j]);
    *(float4*)&dst[((size_t)(b * LL + l0 + t0 + j) << 7) + d0] = v;
  }
}

// ---------------------------------------------------------------------------
// K4: causal depthwise conv1d + SiLU -> xc; x_proj -> (dt_raw,Bm,Cm);
//     dt_proj + softplus -> dt.
// ---------------------------------------------------------------------------
__global__ __launch_bounds__(128) void k4_conv_proj(
    const float* __restrict__ xm, const float* __restrict__ convd_w,
    const float* __restrict__ convd_b, const float* __restrict__ xpw,
    const float* __restrict__ dpw, const float* __restrict__ dpb,
    float* __restrict__ xc_g, float* __restrict__ dt_g,
    float* __restrict__ Bm_g, float* __restrict__ Cm_g) {
  __shared__ float xms[11 * 128];
  __shared__ float xcs[8 * 132];
  __shared__ float xpws[128 * 36];
  __shared__ float dbcs[8 * 36];
  int tid = threadIdx.x;
  int blk = blockIdx.x;             // 2048
  int b  = blk >> 9;
  int l0 = (blk & 511) << 3;
  for (int r = 0; r < 11; ++r) {
    int l = l0 - 3 + r;
    xms[r * 128 + tid] = (l >= 0) ? xm[((size_t)(b * LL + l) << 7) + tid] : 0.f;
  }
  for (int i = tid; i < 4608; i += 128) {
    int e = i >> 7, d = i & 127;
    xpws[d * 36 + e] = xpw[i];
  }
  __syncthreads();
  float cw0 = convd_w[tid*4+0], cw1 = convd_w[tid*4+1];
  float cw2 = convd_w[tid*4+2], cw3 = convd_w[tid*4+3];
  float cb = convd_b[tid];
  #pragma unroll
  for (int t = 0; t < 8; ++t) {
    float pre = cb + cw0 * xms[t*128 + tid] + cw1 * xms[(t+1)*128 + tid]
                   + cw2 * xms[(t+2)*128 + tid] + cw3 * xms[(t+3)*128 + tid];
    float v = pre / (1.f + __expf(-pre));   // silu
    xcs[t * 132 + tid] = v;
    xc_g[((size_t)(b * LL + l0 + t) << 7) + tid] = v;
  }
  __syncthreads();
  for (int p = tid; p < 288; p += 128) {
    int t = p / 36, e = p - t * 36;
    float acc = 0.f;
    #pragma unroll
    for (int d = 0; d < 128; ++d)
      acc += xpws[d * 36 + e] * xcs[t * 132 + d];
    dbcs[t * 36 + e] = acc;
  }
  __syncthreads();
  float w0 = dpw[tid*4+0], w1 = dpw[tid*4+1], w2 = dpw[tid*4+2], w3 = dpw[tid*4+3];
  float bb = dpb[tid];
  #pragma unroll
  for (int t = 0; t < 8; ++t) {
    float raw = bb + w0 * dbcs[t*36+0] + w1 * dbcs[t*36+1]
                   + w2 * dbcs[t*36+2] + w3 * dbcs[t*36+3];
    float sp = (raw > 20.f) ? raw : log1pf(__expf(raw));   // softplus
    dt_g[((size_t)(b * LL + l0 + t) << 7) + tid] = sp;
  }
  int tl = tid >> 4, s = tid & 15;
  Bm_g[((size_t)(b * LL + l0 + tl) << 4) + s] = dbcs[tl * 36 + 4 + s];
  Cm_g[((size_t)(b * LL + l0 + tl) << 4) + s] = dbcs[tl * 36 + 20 + s];
}

// ---------------------------------------------------------------------------
// K5a: per-chunk local scan (h seeded 0) -> h_end, P = prod(exp(dt*A))
// ---------------------------------------------------------------------------
__global__ __launch_bounds__(64) void k5a_chunk(
    const float* __restrict__ dt_g, const float* __restrict__ Bm_g,
    const float* __restrict__ xc_g, const float* __restrict__ A_log,
    float* __restrict__ h_end, float* __restrict__ Pp) {
  int blk = blockIdx.x;
  int dg = blk & 31;
  int c  = (blk >> 5) & 63;
  int b  = blk >> 11;
  int lane = threadIdx.x;
  int s = lane & 15, dl = lane >> 4;
  int d = (dg << 2) + dl;
  float A = -__expf(A_log[d * 16 + s]);
  const float* dt_p = dt_g + ((size_t)b * LL << 7);
  const float* xc_p = xc_g + ((size_t)b * LL << 7);
  const float* Bm_p = Bm_g + ((size_t)b * LL << 4);
  float h = 0.f, p = 1.f;
  int l0 = c << 6;
  #pragma unroll 4
  for (int i = 0; i < 64; ++i) {
    int l = l0 + i;
    float dtv = dt_p[(l << 7) + d];
    float xcv = xc_p[(l << 7) + d];
    float Bv  = Bm_p[(l << 4) + s];
    float dA  = __expf(dtv * A);
    h = h * dA + dtv * Bv * xcv;
    p *= dA;
  }
  size_t o = ((((size_t)b * 64 + c) * 128 + d) << 4) + s;
  h_end[o] = h;
  Pp[o] = p;
}

// ---------------------------------------------------------------------------
// K5b: carry scan over 64 chunks: h_in[c] = H; H = H*P[c] + h_end[c]
// ---------------------------------------------------------------------------
__global__ __launch_bounds__(64) void k5b_carry(
    const float* __restrict__ h_end, const float* __restrict__ Pp,
    float* __restrict__ h_in) {
  int blk = blockIdx.x;   // b*32+dg
  int b = blk >> 5, dg = blk & 31;
  int lane = threadIdx.x;
  size_t base = ((size_t)b * 64) * 2048 + (dg << 6) + lane;
  float H = 0.f;
  for (int c = 0; c < 64; ++c) {
    size_t o = base + (size_t)c * 2048;
    h_in[o] = H;
    H = H * Pp[o] + h_end[o];
  }
}

// ---------------------------------------------------------------------------
// K5c: final scan seeded with h_in; fused gating:
// ys = (y + xc*Dp) * silu(z)  written directly (k6 reads one buffer)
// ---------------------------------------------------------------------------
__global__ __launch_bounds__(64) void k5c_scan(
    const float* __restrict__ dt_g, const float* __restrict__ Bm_g,
    const float* __restrict__ Cm_g, const float* __restrict__ xc_g,
    const float* __restrict__ A_log, const float* __restrict__ h_in,
    const float* __restrict__ z_g, const float* __restrict__ Dp,
    float* __restrict__ ys_g) {
  int blk = blockIdx.x;
  int dg = blk & 31;
  int c  = (blk >> 5) & 63;
  int b  = blk >> 11;
  int lane = threadIdx.x;
  int s = lane & 15, dl = lane >> 4;
  int d = (dg << 2) + dl;
  float A = -__expf(A_log[d * 16 + s]);
  float dpv = Dp[d];
  const float* dt_p = dt_g + ((size_t)b * LL << 7);
  const float* xc_p = xc_g + ((size_t)b * LL << 7);
  const float* Bm_p = Bm_g + ((size_t)b * LL << 4);
  const float* Cm_p = Cm_g + ((size_t)b * LL << 4);
  const float* z_p  = z_g  + ((size_t)b * LL << 7);
  float* ys_p = ys_g + ((size_t)b * LL << 7);
  float h = h_in[((((size_t)b * 64 + c) * 128 + d) << 4) + s];
  int l0 = c << 6;
  #pragma unroll 4
  for (int i = 0; i < 64; ++i) {
    int l = l0 + i;
    float dtv = dt_p[(l << 7) + d];
    float xcv = xc_p[(l << 7) + d];
    float Bv  = Bm_p[(l << 4) + s];
    float Cv  = Cm_p[(l << 4) + s];
    float dA  = __expf(dtv * A);
    h = h * dA + dtv * Bv * xcv;
    float pr = h * Cv;
    pr += __shfl_xor(pr, 1, 64);
    pr += __shfl_xor(pr, 2, 64);
    pr += __shfl_xor(pr, 4, 64);
    pr += __shfl_xor(pr, 8, 64);
    if (s == 0) {
      float zz = z_p[(l << 7) + d];
      float sil = zz / (1.f + __expf(-zz));
      ys_p[(l << 7) + d] = (pr + xcv * dpv) * sil;
    }
  }
}

// ---------------------------------------------------------------------------
// K6: out_tok = ys@out_proj^T + seq; write NCHW. Register-blocked like K3.
// 64-token tile, 256 thr; thread owns 4t x 4c accumulator.
// ---------------------------------------------------------------------------
__global__ __launch_bounds__(256) void k6_out(
    const float* __restrict__ ys_g, const float* __restrict__ opw,
    const float* __restrict__ seq, float* __restrict__ out) {
  __shared__ __align__(16) float wsm[128 * 68];   // [d][c], pad 68
  __shared__ __align__(16) float ysm[128 * 68];   // [d][t], pad 68 (reused as outs)
  __shared__ float seqs[64 * 65];                 // [c][t]
  int tid = threadIdx.x;
  int blk = blockIdx.x;             // 256
  int b  = blk >> 6;
  int l0 = (blk & 63) << 6;
  for (int i = tid; i < 8192; i += 256) {
    int c = i >> 7, d = i & 127;
    wsm[d * 68 + c] = opw[i];
  }
  for (int i = tid; i < 8192; i += 256) {
    int t = i >> 7, d = i & 127;
    ysm[d * 68 + t] = ys_g[((size_t)(b * LL + l0) << 7) + i];
  }
  for (int i = tid; i < 4096; i += 256) {
    int t = i >> 6, c = i & 63;
    seqs[c * 65 + t] = seq[((size_t)(b * LL + l0) << 6) + i];
  }
  __syncthreads();
  int c0 = (tid & 15) << 2;   // 0..60
  int t0 = (tid >> 4) << 2;   // 0..60
  float acc[4][4] = {};       // [t][c]
  #pragma unroll 8
  for (int d = 0; d < 128; ++d) {
    const float4 w4 = *(const float4*)&wsm[d * 68 + c0];
    const float4 y4 = *(const float4*)&ysm[d * 68 + t0];
    const float wv[4] = {w4.x, w4.y, w4.z, w4.w};
    const float yv[4] = {y4.x, y4.y, y4.z, y4.w};
    #pragma unroll
    for (int i = 0; i < 4; ++i)
      #pragma unroll
      for (int j = 0; j < 4; ++j)
        acc[i][j] = fmaf(yv[i], wv[j], acc[i][j]);
  }
  __syncthreads();            // done reading ysm; reuse as outs
  float* outs = ysm;
  #pragma unroll
  for (int i = 0; i < 4; ++i)
    #pragma unroll
    for (int j = 0; j < 4; ++j)
      outs[(c0 + j) * 65 + t0 + i] = acc[i][j];
  __syncthreads();
  for (int i = tid; i < 4096; i += 256) {
    int c = i >> 6, t = i & 63;
    out[((size_t)(b * 64 + c) << 12) + l0 + t] = outs[c * 65 + t] + seqs[c * 65 + t];
  }
}

// ---------------------------------------------------------------------------
extern "C" void kernel_launch(void* const* d_in, const int* in_sizes, int n_in,
                              void* d_out, int out_size, void* d_ws, size_t ws_size,
                              hipStream_t stream) {
  const float* x       = (const float*)d_in[0];
  const float* dwh_w   = (const float*)d_in[1];
  const float* dwh_b   = (const float*)d_in[2];
  const float* dww_w   = (const float*)d_in[3];
  const float* dww_b   = (const float*)d_in[4];
  const float* conv_w  = (const float*)d_in[5];
  const float* conv_b  = (const float*)d_in[6];
  const float* bn_g    = (const float*)d_in[7];
  const float* bn_b    = (const float*)d_in[8];
  const float* bn_m    = (const float*)d_in[9];
  const float* bn_v    = (const float*)d_in[10];
  const float* ln_g    = (const float*)d_in[11];
  const float* ln_b    = (const float*)d_in[12];
  const float* ipw     = (const float*)d_in[13];
  const float* convd_w = (const float*)d_in[14];
  const float* convd_b = (const float*)d_in[15];
  const float* xpw     = (const float*)d_in[16];
  const float* dpw     = (const float*)d_in[17];
  const float* dpb     = (const float*)d_in[18];
  const float* A_log   = (const float*)d_in[19];
  const float* Dp      = (const float*)d_in[20];
  const float* opw     = (const float*)d_in[21];
  float* out = (float*)d_out;

  float* ws = (float*)d_ws;
  const size_t M = 1048576;  // 1M floats
  float* t_buf = ws + 0;          // 1M  (dead after K2 -> reused h_in/P)
  float* seq   = ws + M;          // 1M  (live to K6)
  float* hn    = ws + 2 * M;      // 1M  (dead after K3 -> Bm/Cm/h_end)
  float* Bm    = ws + 2 * M;                    // 256K floats
  float* Cm    = ws + 2 * M + 262144;           // 256K floats
  float* h_end = ws + 2 * M + 524288;           // 512K floats (hn tail)
  float* xm    = ws + 3 * M;      // 2M  (dead after K4 -> ys)
  float* ys    = ws + 3 * M;      // 2M  (written K5c)
  float* z_buf = ws + 5 * M;      // 2M
  float* xc    = ws + 7 * M;      // 2M
  float* dt    = ws + 9 * M;      // 2M   => total 11M floats = 44 MB
  float* h_in  = ws + 0;          // 512K floats (t_buf)
  float* P_buf = ws + 524288;     // 512K floats (t_buf tail)

  k1_axial<<<4096, 256, 0, stream>>>(x, dwh_w, dwh_b, dww_w, dww_b, t_buf);
  k2_conv1x1_ln<<<256, 256, 0, stream>>>(t_buf, conv_w, conv_b, bn_g, bn_b,
                                         bn_m, bn_v, ln_g, ln_b, seq, hn);
  k3_inproj<<<dim3(256, 2), 256, 0, stream>>>(hn, ipw, xm, z_buf);
  k4_conv_proj<<<2048, 128, 0, stream>>>(xm, convd_w, convd_b, xpw, dpw, dpb,
                                         xc, dt, Bm, Cm);
  k5a_chunk<<<8192, 64, 0, stream>>>(dt, Bm, xc, A_log, h_end, P_buf);
  k5b_carry<<<128, 64, 0, stream>>>(h_end, P_buf, h_in);
  k5c_scan<<<8192, 64, 0, stream>>>(dt, Bm, Cm, xc, A_log, h_in, z_buf, Dp, ys);
  k6_out<<<256, 256, 0, stream>>>(ys, opw, seq, out);
}

// Round 4
// 241.174 us; speedup vs baseline: 7.6196x; 1.0991x over previous
//
#include <hip/hip_runtime.h>
#include <hip/hip_bf16.h>
#include <math.h>

#define BB 4
#define CC 64
#define HH 64
#define WW 64
#define LL 4096   // HH*WW
#define DI 128    // D_INNER
#define DS 16     // D_STATE
#define NC 128    // scan chunks
#define CL 32     // chunk length (NC*CL = LL)

// ---------------------------------------------------------------------------
// K1: axial depthwise convs + residual + biases -> t[b,c,h,w]
// ---------------------------------------------------------------------------
__global__ __launch_bounds__(256) void k1_axial(
    const float* __restrict__ x, const float* __restrict__ dwh_w,
    const float* __restrict__ dwh_b, const float* __restrict__ dww_w,
    const float* __restrict__ dww_b, float* __restrict__ t_out) {
  int idx = blockIdx.x * 256 + threadIdx.x;   // < 4*64*64*64 = 1048576
  int w = idx & 63;
  int h = (idx >> 6) & 63;
  int c = (idx >> 12) & 63;
  float xc_ = x[idx];
  float up = (h > 0)  ? x[idx - 64] : 0.f;
  float dn = (h < 63) ? x[idx + 64] : 0.f;
  float lf = (w > 0)  ? x[idx - 1]  : 0.f;
  float rt = (w < 63) ? x[idx + 1]  : 0.f;
  float th = dwh_w[c*3+0]*up + dwh_w[c*3+1]*xc_ + dwh_w[c*3+2]*dn;
  float tw = dww_w[c*3+0]*lf + dww_w[c*3+1]*xc_ + dww_w[c*3+2]*rt;
  t_out[idx] = xc_ + th + dwh_b[c] + tw + dww_b[c];
}

// ---------------------------------------------------------------------------
// K2: 1x1 conv + BN + ReLU -> seq[b,l,c]; LayerNorm -> hn[b,l,c]
// ---------------------------------------------------------------------------
__global__ __launch_bounds__(256) void k2_conv1x1_ln(
    const float* __restrict__ t_in, const float* __restrict__ conv_w,
    const float* __restrict__ conv_b, const float* __restrict__ bn_g,
    const float* __restrict__ bn_b, const float* __restrict__ bn_m,
    const float* __restrict__ bn_v, const float* __restrict__ ln_g,
    const float* __restrict__ ln_b, float* __restrict__ seq,
    float* __restrict__ hn) {
  __shared__ float wsm[64 * 65];
  __shared__ float tsm[64 * 65];
  int tid = threadIdx.x;
  int blk = blockIdx.x;           // 256 blocks
  int b  = blk >> 6;
  int p0 = (blk & 63) << 6;       // 64 pixels
  for (int i = tid; i < 4096; i += 256) {
    int co = i >> 6, ci = i & 63;
    wsm[ci * 65 + co] = conv_w[i];                 // transpose, pad 65
  }
  for (int i = tid; i < 4096; i += 256) {
    int ci = i >> 6, pl = i & 63;
    tsm[pl * 65 + ci] = t_in[((b * 64 + ci) << 12) + p0 + pl];  // coalesced
  }
  __syncthreads();
  int co = tid & 63;
  int pw = tid >> 6;  // 0..3
  float scale = bn_g[co] * rsqrtf(bn_v[co] + 1e-5f);
  float shift = bn_b[co] - bn_m[co] * scale;
  float cb = conv_b[co];
  float lg = ln_g[co], lb = ln_b[co];
  for (int j = 0; j < 16; ++j) {
    int pl = j * 4 + pw;
    float acc = 0.f;
    #pragma unroll
    for (int ci = 0; ci < 64; ++ci)
      acc += wsm[ci * 65 + co] * tsm[pl * 65 + ci];
    float v = (acc + cb) * scale + shift;
    v = fmaxf(v, 0.f);
    int p = p0 + pl;
    seq[((size_t)(b * LL + p) << 6) + co] = v;
    float sum = v, sq = v * v;
    #pragma unroll
    for (int off = 1; off < 64; off <<= 1) {
      sum += __shfl_xor(sum, off, 64);
      sq  += __shfl_xor(sq,  off, 64);
    }
    float mu  = sum * (1.f / 64.f);
    float var = sq * (1.f / 64.f) - mu * mu;
    float inv = rsqrtf(var + 1e-5f);
    hn[((size_t)(b * LL + p) << 6) + co] = (v - mu) * inv * lg + lb;
  }
}

// ---------------------------------------------------------------------------
// K3: in_proj, register-blocked. 64-token tile, 256 thr, grid.y = half.
// ---------------------------------------------------------------------------
__global__ __launch_bounds__(256) void k3_inproj(
    const float* __restrict__ hn, const float* __restrict__ ipw,
    float* __restrict__ xm, float* __restrict__ z) {
  __shared__ __align__(16) float wsm[64 * 132];   // [c][d], pad 132
  __shared__ __align__(16) float hsm[64 * 68];    // [c][t], pad 68
  int tid = threadIdx.x;
  int half = blockIdx.y;
  int blk = blockIdx.x;             // 256
  int b  = blk >> 6;
  int l0 = (blk & 63) << 6;         // 64 tokens
  const float* wsrc = ipw + half * 8192;   // [128 d][64 c]
  for (int i = tid; i < 8192; i += 256) {
    int d = i >> 6, c = i & 63;
    wsm[c * 132 + d] = wsrc[i];
  }
  for (int i = tid; i < 4096; i += 256) {
    int t = i >> 6, c = i & 63;
    hsm[c * 68 + t] = hn[((size_t)(b * LL + l0) << 6) + i];
  }
  __syncthreads();
  int d0 = (tid & 31) << 2;   // 0..124
  int t0 = (tid >> 5) << 3;   // 0..56
  float acc[4][8] = {};
  #pragma unroll 8
  for (int c = 0; c < 64; ++c) {
    const float4 w4 = *(const float4*)&wsm[c * 132 + d0];
    const float4 h0 = *(const float4*)&hsm[c * 68 + t0];
    const float4 h1 = *(const float4*)&hsm[c * 68 + t0 + 4];
    const float wv[4] = {w4.x, w4.y, w4.z, w4.w};
    const float hv[8] = {h0.x, h0.y, h0.z, h0.w, h1.x, h1.y, h1.z, h1.w};
    #pragma unroll
    for (int i = 0; i < 4; ++i)
      #pragma unroll
      for (int j = 0; j < 8; ++j)
        acc[i][j] = fmaf(wv[i], hv[j], acc[i][j]);
  }
  float* dst = half ? z : xm;
  #pragma unroll
  for (int j = 0; j < 8; ++j) {
    float4 v = make_float4(acc[0][j], acc[1][j], acc[2][j], acc[3][j]);
    *(float4*)&dst[((size_t)(b * LL + l0 + t0 + j) << 7) + d0] = v;
  }
}

// ---------------------------------------------------------------------------
// K4: causal depthwise conv1d + SiLU -> xc; x_proj -> (dt_raw,Bm,Cm);
//     dt_proj + softplus -> dt.
// ---------------------------------------------------------------------------
__global__ __launch_bounds__(128) void k4_conv_proj(
    const float* __restrict__ xm, const float* __restrict__ convd_w,
    const float* __restrict__ convd_b, const float* __restrict__ xpw,
    const float* __restrict__ dpw, const float* __restrict__ dpb,
    float* __restrict__ xc_g, float* __restrict__ dt_g,
    float* __restrict__ Bm_g, float* __restrict__ Cm_g) {
  __shared__ float xms[11 * 128];
  __shared__ float xcs[8 * 132];
  __shared__ float xpws[128 * 36];
  __shared__ float dbcs[8 * 36];
  int tid = threadIdx.x;
  int blk = blockIdx.x;             // 2048
  int b  = blk >> 9;
  int l0 = (blk & 511) << 3;
  for (int r = 0; r < 11; ++r) {
    int l = l0 - 3 + r;
    xms[r * 128 + tid] = (l >= 0) ? xm[((size_t)(b * LL + l) << 7) + tid] : 0.f;
  }
  for (int i = tid; i < 4608; i += 128) {
    int e = i >> 7, d = i & 127;
    xpws[d * 36 + e] = xpw[i];
  }
  __syncthreads();
  float cw0 = convd_w[tid*4+0], cw1 = convd_w[tid*4+1];
  float cw2 = convd_w[tid*4+2], cw3 = convd_w[tid*4+3];
  float cb = convd_b[tid];
  #pragma unroll
  for (int t = 0; t < 8; ++t) {
    float pre = cb + cw0 * xms[t*128 + tid] + cw1 * xms[(t+1)*128 + tid]
                   + cw2 * xms[(t+2)*128 + tid] + cw3 * xms[(t+3)*128 + tid];
    float v = pre / (1.f + __expf(-pre));   // silu
    xcs[t * 132 + tid] = v;
    xc_g[((size_t)(b * LL + l0 + t) << 7) + tid] = v;
  }
  __syncthreads();
  for (int p = tid; p < 288; p += 128) {
    int t = p / 36, e = p - t * 36;
    float acc = 0.f;
    #pragma unroll
    for (int d = 0; d < 128; ++d)
      acc += xpws[d * 36 + e] * xcs[t * 132 + d];
    dbcs[t * 36 + e] = acc;
  }
  __syncthreads();
  float w0 = dpw[tid*4+0], w1 = dpw[tid*4+1], w2 = dpw[tid*4+2], w3 = dpw[tid*4+3];
  float bb = dpb[tid];
  #pragma unroll
  for (int t = 0; t < 8; ++t) {
    float raw = bb + w0 * dbcs[t*36+0] + w1 * dbcs[t*36+1]
                   + w2 * dbcs[t*36+2] + w3 * dbcs[t*36+3];
    float sp = (raw > 20.f) ? raw : log1pf(__expf(raw));   // softplus
    dt_g[((size_t)(b * LL + l0 + t) << 7) + tid] = sp;
  }
  int tl = tid >> 4, s = tid & 15;
  Bm_g[((size_t)(b * LL + l0 + tl) << 4) + s] = dbcs[tl * 36 + 4 + s];
  Cm_g[((size_t)(b * LL + l0 + tl) << 4) + s] = dbcs[tl * 36 + 20 + s];
}

// ---------------------------------------------------------------------------
// K5a: per-chunk local scan, lane-owns-d (16 states in registers).
// grid: b*NC blocks x 128 thr (lane = d). CL=32 steps.
// Outputs h_end/P laid out [b][c][d][16].
// ---------------------------------------------------------------------------
__global__ __launch_bounds__(128) void k5a_chunk(
    const float* __restrict__ dt_g, const float* __restrict__ Bm_g,
    const float* __restrict__ xc_g, const float* __restrict__ A_log,
    float* __restrict__ h_end, float* __restrict__ Pp) {
  __shared__ float bsm[CL * 16];
  int blk = blockIdx.x;             // b*NC + c
  int b = blk >> 7, c = blk & (NC - 1);
  int d = threadIdx.x;
  int l0 = c * CL;
  const float* dt_p = dt_g + ((size_t)b << 19);
  const float* xc_p = xc_g + ((size_t)b << 19);
  const float* Bm_p = Bm_g + ((size_t)b << 16);
  for (int j = d; j < CL * 16; j += 128) bsm[j] = Bm_p[(l0 << 4) + j];
  __syncthreads();
  float A[16], h[16], p[16];
  #pragma unroll
  for (int s = 0; s < 16; ++s) {
    A[s] = -__expf(A_log[d * 16 + s]);
    h[s] = 0.f; p[s] = 1.f;
  }
  #pragma unroll 4
  for (int i = 0; i < CL; ++i) {
    int l = l0 + i;
    float dtv = dt_p[(l << 7) + d];
    float xcv = xc_p[(l << 7) + d];
    float dtx = dtv * xcv;
    #pragma unroll
    for (int s = 0; s < 16; ++s) {
      float dA = __expf(dtv * A[s]);
      h[s] = fmaf(h[s], dA, dtx * bsm[i * 16 + s]);
      p[s] *= dA;
    }
  }
  float* he = h_end + ((((size_t)blk << 7) + d) << 4);
  float* pe = Pp    + ((((size_t)blk << 7) + d) << 4);
  #pragma unroll
  for (int q = 0; q < 4; ++q) {
    *(float4*)&he[q * 4] = make_float4(h[q*4], h[q*4+1], h[q*4+2], h[q*4+3]);
    *(float4*)&pe[q * 4] = make_float4(p[q*4], p[q*4+1], p[q*4+2], p[q*4+3]);
  }
}

// ---------------------------------------------------------------------------
// K5b: carry scan over NC chunks. thread per (b,d,s): 8192 thr = 64 blk x 128.
// h_in[c] = H; H = H*P[c] + h_end[c]
// ---------------------------------------------------------------------------
__global__ __launch_bounds__(128) void k5b_carry(
    const float* __restrict__ h_end, const float* __restrict__ Pp,
    float* __restrict__ h_in) {
  int g = blockIdx.x * 128 + threadIdx.x;  // [0, 8192)
  int b = g >> 11;
  int r = g & 2047;                        // d*16+s
  size_t base = ((size_t)b << 18) + r;     // b*NC*2048
  float H = 0.f;
  for (int c = 0; c < NC; ++c) {
    size_t o = base + ((size_t)c << 11);
    h_in[o] = H;
    H = fmaf(H, Pp[o], h_end[o]);
  }
}

// ---------------------------------------------------------------------------
// K5c: final scan seeded with h_in, lane-owns-d; fused gating:
// ys = (y + xc*Dp) * silu(z)
// ---------------------------------------------------------------------------
__global__ __launch_bounds__(128) void k5c_scan(
    const float* __restrict__ dt_g, const float* __restrict__ Bm_g,
    const float* __restrict__ Cm_g, const float* __restrict__ xc_g,
    const float* __restrict__ A_log, const float* __restrict__ h_in,
    const float* __restrict__ z_g, const float* __restrict__ Dp,
    float* __restrict__ ys_g) {
  __shared__ float bsm[CL * 16];
  __shared__ float csm[CL * 16];
  int blk = blockIdx.x;             // b*NC + c
  int b = blk >> 7, c = blk & (NC - 1);
  int d = threadIdx.x;
  int l0 = c * CL;
  const float* dt_p = dt_g + ((size_t)b << 19);
  const float* xc_p = xc_g + ((size_t)b << 19);
  const float* z_p  = z_g  + ((size_t)b << 19);
  const float* Bm_p = Bm_g + ((size_t)b << 16);
  const float* Cm_p = Cm_g + ((size_t)b << 16);
  float* ys_p = ys_g + ((size_t)b << 19);
  for (int j = d; j < CL * 16; j += 128) {
    bsm[j] = Bm_p[(l0 << 4) + j];
    csm[j] = Cm_p[(l0 << 4) + j];
  }
  __syncthreads();
  float A[16], h[16];
  const float* hi = h_in + ((((size_t)blk << 7) + d) << 4);
  #pragma unroll
  for (int q = 0; q < 4; ++q) {
    float4 h4 = *(const float4*)&hi[q * 4];
    h[q*4] = h4.x; h[q*4+1] = h4.y; h[q*4+2] = h4.z; h[q*4+3] = h4.w;
  }
  #pragma unroll
  for (int s = 0; s < 16; ++s) A[s] = -__expf(A_log[d * 16 + s]);
  float dpv = Dp[d];
  #pragma unroll 4
  for (int i = 0; i < CL; ++i) {
    int l = l0 + i;
    float dtv = dt_p[(l << 7) + d];
    float xcv = xc_p[(l << 7) + d];
    float dtx = dtv * xcv;
    float y = 0.f;
    #pragma unroll
    for (int s = 0; s < 16; ++s) {
      float dA = __expf(dtv * A[s]);
      h[s] = fmaf(h[s], dA, dtx * bsm[i * 16 + s]);
      y = fmaf(h[s], csm[i * 16 + s], y);
    }
    float zz = z_p[(l << 7) + d];
    float sil = zz / (1.f + __expf(-zz));
    ys_p[(l << 7) + d] = (y + xcv * dpv) * sil;
  }
}

// ---------------------------------------------------------------------------
// K6: out_tok = ys@out_proj^T + seq; write NCHW. Register-blocked.
// ---------------------------------------------------------------------------
__global__ __launch_bounds__(256) void k6_out(
    const float* __restrict__ ys_g, const float* __restrict__ opw,
    const float* __restrict__ seq, float* __restrict__ out) {
  __shared__ __align__(16) float wsm[128 * 68];   // [d][c], pad 68
  __shared__ __align__(16) float ysm[128 * 68];   // [d][t], pad 68 (reused as outs)
  __shared__ float seqs[64 * 65];                 // [c][t]
  int tid = threadIdx.x;
  int blk = blockIdx.x;             // 256
  int b  = blk >> 6;
  int l0 = (blk & 63) << 6;
  for (int i = tid; i < 8192; i += 256) {
    int c = i >> 7, d = i & 127;
    wsm[d * 68 + c] = opw[i];
  }
  for (int i = tid; i < 8192; i += 256) {
    int t = i >> 7, d = i & 127;
    ysm[d * 68 + t] = ys_g[((size_t)(b * LL + l0) << 7) + i];
  }
  for (int i = tid; i < 4096; i += 256) {
    int t = i >> 6, c = i & 63;
    seqs[c * 65 + t] = seq[((size_t)(b * LL + l0) << 6) + i];
  }
  __syncthreads();
  int c0 = (tid & 15) << 2;   // 0..60
  int t0 = (tid >> 4) << 2;   // 0..60
  float acc[4][4] = {};       // [t][c]
  #pragma unroll 8
  for (int d = 0; d < 128; ++d) {
    const float4 w4 = *(const float4*)&wsm[d * 68 + c0];
    const float4 y4 = *(const float4*)&ysm[d * 68 + t0];
    const float wv[4] = {w4.x, w4.y, w4.z, w4.w};
    const float yv[4] = {y4.x, y4.y, y4.z, y4.w};
    #pragma unroll
    for (int i = 0; i < 4; ++i)
      #pragma unroll
      for (int j = 0; j < 4; ++j)
        acc[i][j] = fmaf(yv[i], wv[j], acc[i][j]);
  }
  __syncthreads();            // done reading ysm; reuse as outs
  float* outs = ysm;
  #pragma unroll
  for (int i = 0; i < 4; ++i)
    #pragma unroll
    for (int j = 0; j < 4; ++j)
      outs[(c0 + j) * 65 + t0 + i] = acc[i][j];
  __syncthreads();
  for (int i = tid; i < 4096; i += 256) {
    int c = i >> 6, t = i & 63;
    out[((size_t)(b * 64 + c) << 12) + l0 + t] = outs[c * 65 + t] + seqs[c * 65 + t];
  }
}

// ---------------------------------------------------------------------------
extern "C" void kernel_launch(void* const* d_in, const int* in_sizes, int n_in,
                              void* d_out, int out_size, void* d_ws, size_t ws_size,
                              hipStream_t stream) {
  const float* x       = (const float*)d_in[0];
  const float* dwh_w   = (const float*)d_in[1];
  const float* dwh_b   = (const float*)d_in[2];
  const float* dww_w   = (const float*)d_in[3];
  const float* dww_b   = (const float*)d_in[4];
  const float* conv_w  = (const float*)d_in[5];
  const float* conv_b  = (const float*)d_in[6];
  const float* bn_g    = (const float*)d_in[7];
  const float* bn_b    = (const float*)d_in[8];
  const float* bn_m    = (const float*)d_in[9];
  const float* bn_v    = (const float*)d_in[10];
  const float* ln_g    = (const float*)d_in[11];
  const float* ln_b    = (const float*)d_in[12];
  const float* ipw     = (const float*)d_in[13];
  const float* convd_w = (const float*)d_in[14];
  const float* convd_b = (const float*)d_in[15];
  const float* xpw     = (const float*)d_in[16];
  const float* dpw     = (const float*)d_in[17];
  const float* dpb     = (const float*)d_in[18];
  const float* A_log   = (const float*)d_in[19];
  const float* Dp      = (const float*)d_in[20];
  const float* opw     = (const float*)d_in[21];
  float* out = (float*)d_out;

  float* ws = (float*)d_ws;
  const size_t M = 1048576;  // 1M floats
  // Liveness: t_buf dead after K2 -> h_in (1M floats).
  //           xm dead after K4 -> h_end@[3M,4M) P@[4M,5M) (dead after K5b)
  //           -> ys@[3M,5M) written by K5c after K5b consumed h_end/P.
  float* t_buf = ws + 0;          // 1M
  float* seq   = ws + M;          // 1M  (live to K6)
  float* hn    = ws + 2 * M;      // 1M  (dead after K3 -> Bm/Cm)
  float* Bm    = ws + 2 * M;                    // 256K floats
  float* Cm    = ws + 2 * M + 262144;           // 256K floats
  float* xm    = ws + 3 * M;      // 2M  (dead after K4)
  float* h_end = ws + 3 * M;      // 1M  (K5a -> K5b)
  float* P_buf = ws + 4 * M;      // 1M  (K5a -> K5b)
  float* ys    = ws + 3 * M;      // 2M  (written K5c)
  float* z_buf = ws + 5 * M;      // 2M
  float* xc    = ws + 7 * M;      // 2M
  float* dt    = ws + 9 * M;      // 2M   => total 11M floats = 44 MB
  float* h_in  = ws + 0;          // 1M  (t_buf region, K5b -> K5c)

  k1_axial<<<4096, 256, 0, stream>>>(x, dwh_w, dwh_b, dww_w, dww_b, t_buf);
  k2_conv1x1_ln<<<256, 256, 0, stream>>>(t_buf, conv_w, conv_b, bn_g, bn_b,
                                         bn_m, bn_v, ln_g, ln_b, seq, hn);
  k3_inproj<<<dim3(256, 2), 256, 0, stream>>>(hn, ipw, xm, z_buf);
  k4_conv_proj<<<2048, 128, 0, stream>>>(xm, convd_w, convd_b, xpw, dpw, dpb,
                                         xc, dt, Bm, Cm);
  k5a_chunk<<<BB * NC, 128, 0, stream>>>(dt, Bm, xc, A_log, h_end, P_buf);
  k5b_carry<<<64, 128, 0, stream>>>(h_end, P_buf, h_in);
  k5c_scan<<<BB * NC, 128, 0, stream>>>(dt, Bm, Cm, xc, A_log, h_in, z_buf, Dp, ys);
  k6_out<<<256, 256, 0, stream>>>(ys, opw, seq, out);
}

// Round 5
// 224.925 us; speedup vs baseline: 8.1700x; 1.0722x over previous
//
#include <hip/hip_runtime.h>
#include <hip/hip_bf16.h>
#include <math.h>

#define BB 4
#define CC 64
#define LL 4096   // 64*64 tokens per batch
#define DI 128    // D_INNER
#define DS 16     // D_STATE
#define NC 64     // scan chunks
#define CL 64     // chunk length (NC*CL = LL)

// ---------------------------------------------------------------------------
// K12: axial DW conv + 1x1 conv + BN + ReLU -> seqT[b,c,l] (NCHW layout);
//      LayerNorm -> hn[b,l,c].  Block per (b, h-row): 256 blocks x 256 thr.
// ---------------------------------------------------------------------------
__global__ __launch_bounds__(256) void k12_front(
    const float* __restrict__ x, const float* __restrict__ dwh_w,
    const float* __restrict__ dwh_b, const float* __restrict__ dww_w,
    const float* __restrict__ dww_b, const float* __restrict__ conv_w,
    const float* __restrict__ conv_b, const float* __restrict__ bn_g,
    const float* __restrict__ bn_b, const float* __restrict__ bn_m,
    const float* __restrict__ bn_v, const float* __restrict__ ln_g,
    const float* __restrict__ ln_b, float* __restrict__ seqT,
    float* __restrict__ hn) {
  __shared__ __align__(16) float tsm[64 * 68];   // [ci][w]
  __shared__ __align__(16) float wt[64 * 68];    // [ci][co] (conv_w^T)
  __shared__ float vsm[64 * 65];                 // [w][co]
  int tid = threadIdx.x;
  int blk = blockIdx.x;
  int b = blk >> 6, h = blk & 63;
  for (int i = tid; i < 4096; i += 256) {
    int co = i >> 6, ci = i & 63;
    wt[ci * 68 + co] = conv_w[i];
  }
  for (int i = tid; i < 4096; i += 256) {
    int c = i >> 6, w = i & 63;
    int base = ((b * 64 + c) << 12) + (h << 6) + w;
    float cen = x[base];
    float up = (h > 0)  ? x[base - 64] : 0.f;
    float dn = (h < 63) ? x[base + 64] : 0.f;
    float lf = (w > 0)  ? x[base - 1]  : 0.f;
    float rt = (w < 63) ? x[base + 1]  : 0.f;
    float t = cen + dwh_w[c*3]*up + dwh_w[c*3+1]*cen + dwh_w[c*3+2]*dn + dwh_b[c]
                  + dww_w[c*3]*lf + dww_w[c*3+1]*cen + dww_w[c*3+2]*rt + dww_b[c];
    tsm[c * 68 + w] = t;
  }
  __syncthreads();
  int co0 = (tid & 15) << 2;
  int w0  = (tid >> 4) << 2;
  float acc[4][4] = {};   // [co][w]
  #pragma unroll 8
  for (int ci = 0; ci < 64; ++ci) {
    const float4 w4 = *(const float4*)&wt[ci * 68 + co0];
    const float4 t4 = *(const float4*)&tsm[ci * 68 + w0];
    const float wv[4] = {w4.x, w4.y, w4.z, w4.w};
    const float tv[4] = {t4.x, t4.y, t4.z, t4.w};
    #pragma unroll
    for (int jc = 0; jc < 4; ++jc)
      #pragma unroll
      for (int iw = 0; iw < 4; ++iw)
        acc[jc][iw] = fmaf(wv[jc], tv[iw], acc[jc][iw]);
  }
  #pragma unroll
  for (int j = 0; j < 4; ++j) {
    int co = co0 + j;
    float sc = bn_g[co] * rsqrtf(bn_v[co] + 1e-5f);
    float sh = bn_b[co] - bn_m[co] * sc;
    float cb = conv_b[co];
    float4 o4;
    float* oo = (float*)&o4;
    #pragma unroll
    for (int i = 0; i < 4; ++i) {
      float v = fmaxf(fmaf(acc[j][i] + cb, sc, sh), 0.f);
      vsm[(w0 + i) * 65 + co] = v;
      oo[i] = v;
    }
    *(float4*)&seqT[((size_t)(b * 64 + co) << 12) + (h << 6) + w0] = o4;
  }
  __syncthreads();
  int lane = tid & 63, wv_ = tid >> 6;
  float lg = ln_g[lane], lb = ln_b[lane];
  for (int k = 0; k < 16; ++k) {
    int w = wv_ * 16 + k;
    float v = vsm[w * 65 + lane];
    float sum = v, sq = v * v;
    #pragma unroll
    for (int off = 1; off < 64; off <<= 1) {
      sum += __shfl_xor(sum, off, 64);
      sq  += __shfl_xor(sq,  off, 64);
    }
    float mu  = sum * (1.f / 64.f);
    float var = sq * (1.f / 64.f) - mu * mu;
    float inv = rsqrtf(var + 1e-5f);
    hn[((size_t)((b << 12) + (h << 6) + w) << 6) + lane] = (v - mu) * inv * lg + lb;
  }
}

// ---------------------------------------------------------------------------
// K3: in_proj, register-blocked. 64-token tile, 256 thr, grid.y = half.
// ---------------------------------------------------------------------------
__global__ __launch_bounds__(256) void k3_inproj(
    const float* __restrict__ hn, const float* __restrict__ ipw,
    float* __restrict__ xm, float* __restrict__ z) {
  __shared__ __align__(16) float wsm[64 * 132];   // [c][d]
  __shared__ __align__(16) float hsm[64 * 68];    // [c][t]
  int tid = threadIdx.x;
  int half = blockIdx.y;
  int blk = blockIdx.x;             // 256
  int b  = blk >> 6;
  int l0 = (blk & 63) << 6;
  const float* wsrc = ipw + half * 8192;
  for (int i = tid; i < 8192; i += 256) {
    int d = i >> 6, c = i & 63;
    wsm[c * 132 + d] = wsrc[i];
  }
  for (int i = tid; i < 4096; i += 256) {
    int t = i >> 6, c = i & 63;
    hsm[c * 68 + t] = hn[((size_t)(b * LL + l0) << 6) + i];
  }
  __syncthreads();
  int d0 = (tid & 31) << 2;
  int t0 = (tid >> 5) << 3;
  float acc[4][8] = {};
  #pragma unroll 8
  for (int c = 0; c < 64; ++c) {
    const float4 w4 = *(const float4*)&wsm[c * 132 + d0];
    const float4 h0 = *(const float4*)&hsm[c * 68 + t0];
    const float4 h1 = *(const float4*)&hsm[c * 68 + t0 + 4];
    const float wv[4] = {w4.x, w4.y, w4.z, w4.w};
    const float hv[8] = {h0.x, h0.y, h0.z, h0.w, h1.x, h1.y, h1.z, h1.w};
    #pragma unroll
    for (int i = 0; i < 4; ++i)
      #pragma unroll
      for (int j = 0; j < 8; ++j)
        acc[i][j] = fmaf(wv[i], hv[j], acc[i][j]);
  }
  float* dst = half ? z : xm;
  #pragma unroll
  for (int j = 0; j < 8; ++j) {
    float4 v = make_float4(acc[0][j], acc[1][j], acc[2][j], acc[3][j]);
    *(float4*)&dst[((size_t)(b * LL + l0 + t0 + j) << 7) + d0] = v;
  }
}

// ---------------------------------------------------------------------------
// K4: causal depthwise conv1d + SiLU -> xc; x_proj -> (dt_raw,Bm,Cm);
//     dt_proj + softplus -> dt.
// ---------------------------------------------------------------------------
__global__ __launch_bounds__(128) void k4_conv_proj(
    const float* __restrict__ xm, const float* __restrict__ convd_w,
    const float* __restrict__ convd_b, const float* __restrict__ xpw,
    const float* __restrict__ dpw, const float* __restrict__ dpb,
    float* __restrict__ xc_g, float* __restrict__ dt_g,
    float* __restrict__ Bm_g, float* __restrict__ Cm_g) {
  __shared__ float xms[11 * 128];
  __shared__ float xcs[8 * 132];
  __shared__ float xpws[128 * 36];
  __shared__ float dbcs[8 * 36];
  int tid = threadIdx.x;
  int blk = blockIdx.x;             // 2048
  int b  = blk >> 9;
  int l0 = (blk & 511) << 3;
  for (int r = 0; r < 11; ++r) {
    int l = l0 - 3 + r;
    xms[r * 128 + tid] = (l >= 0) ? xm[((size_t)(b * LL + l) << 7) + tid] : 0.f;
  }
  for (int i = tid; i < 4608; i += 128) {
    int e = i >> 7, d = i & 127;
    xpws[d * 36 + e] = xpw[i];
  }
  __syncthreads();
  float cw0 = convd_w[tid*4+0], cw1 = convd_w[tid*4+1];
  float cw2 = convd_w[tid*4+2], cw3 = convd_w[tid*4+3];
  float cb = convd_b[tid];
  #pragma unroll
  for (int t = 0; t < 8; ++t) {
    float pre = cb + cw0 * xms[t*128 + tid] + cw1 * xms[(t+1)*128 + tid]
                   + cw2 * xms[(t+2)*128 + tid] + cw3 * xms[(t+3)*128 + tid];
    float v = pre / (1.f + __expf(-pre));   // silu
    xcs[t * 132 + tid] = v;
    xc_g[((size_t)(b * LL + l0 + t) << 7) + tid] = v;
  }
  __syncthreads();
  for (int p = tid; p < 288; p += 128) {
    int t = p / 36, e = p - t * 36;
    float acc = 0.f;
    #pragma unroll
    for (int d = 0; d < 128; ++d)
      acc += xpws[d * 36 + e] * xcs[t * 132 + d];
    dbcs[t * 36 + e] = acc;
  }
  __syncthreads();
  float w0 = dpw[tid*4+0], w1 = dpw[tid*4+1], w2 = dpw[tid*4+2], w3 = dpw[tid*4+3];
  float bb = dpb[tid];
  #pragma unroll
  for (int t = 0; t < 8; ++t) {
    float raw = bb + w0 * dbcs[t*36+0] + w1 * dbcs[t*36+1]
                   + w2 * dbcs[t*36+2] + w3 * dbcs[t*36+3];
    float sp = (raw > 20.f) ? raw : log1pf(__expf(raw));   // softplus
    dt_g[((size_t)(b * LL + l0 + t) << 7) + tid] = sp;
  }
  int tl = tid >> 4, s = tid & 15;
  Bm_g[((size_t)(b * LL + l0 + tl) << 4) + s] = dbcs[tl * 36 + 4 + s];
  Cm_g[((size_t)(b * LL + l0 + tl) << 4) + s] = dbcs[tl * 36 + 20 + s];
}

// ---------------------------------------------------------------------------
// K5a: per-chunk local scan, lane-owns-d. CL=64 steps. B via wave-uniform
// loads (scalar path). Outputs h_end/P at [b][chunk][d][s].
// ---------------------------------------------------------------------------
__global__ __launch_bounds__(128) void k5a_chunk(
    const float* __restrict__ dt_g, const float* __restrict__ Bm_g,
    const float* __restrict__ xc_g, const float* __restrict__ A_log,
    float* __restrict__ h_end, float* __restrict__ Pp) {
  int blk = blockIdx.x;             // b*NC + ch
  int b = blk >> 6, ch = blk & 63;
  int d = threadIdx.x;
  int l0 = ch << 6;
  const float* dt_p = dt_g + ((size_t)b << 19);
  const float* xc_p = xc_g + ((size_t)b << 19);
  const float* Bm_p = Bm_g + ((size_t)b << 16);
  float A[16], h[16], p[16];
  #pragma unroll
  for (int q = 0; q < 4; ++q) {
    float4 a4 = *(const float4*)&A_log[d * 16 + q * 4];
    A[q*4]   = -__expf(a4.x); A[q*4+1] = -__expf(a4.y);
    A[q*4+2] = -__expf(a4.z); A[q*4+3] = -__expf(a4.w);
  }
  #pragma unroll
  for (int s = 0; s < 16; ++s) { h[s] = 0.f; p[s] = 1.f; }
  #pragma unroll 2
  for (int i = 0; i < CL; ++i) {
    int l = l0 + i;
    float dtv = dt_p[(l << 7) + d];
    float xcv = xc_p[(l << 7) + d];
    float dtx = dtv * xcv;
    float Bv[16];
    #pragma unroll
    for (int q = 0; q < 4; ++q) {
      float4 b4 = *(const float4*)&Bm_p[(l << 4) + q * 4];   // wave-uniform
      Bv[q*4] = b4.x; Bv[q*4+1] = b4.y; Bv[q*4+2] = b4.z; Bv[q*4+3] = b4.w;
    }
    #pragma unroll
    for (int s = 0; s < 16; ++s) {
      float dA = __expf(dtv * A[s]);
      h[s] = fmaf(h[s], dA, dtx * Bv[s]);
      p[s] *= dA;
    }
  }
  float* he = h_end + ((((size_t)blk << 7) + d) << 4);
  float* pe = Pp    + ((((size_t)blk << 7) + d) << 4);
  #pragma unroll
  for (int q = 0; q < 4; ++q) {
    *(float4*)&he[q * 4] = make_float4(h[q*4], h[q*4+1], h[q*4+2], h[q*4+3]);
    *(float4*)&pe[q * 4] = make_float4(p[q*4], p[q*4+1], p[q*4+2], p[q*4+3]);
  }
}

// ---------------------------------------------------------------------------
// K5b: carry scan over NC=64 chunks, coalesced rows + prefetch.
// 32 blocks x 256 thr; block owns 256 consecutive r of one b.
// ---------------------------------------------------------------------------
__global__ __launch_bounds__(256) void k5b_carry(
    const float* __restrict__ h_end, const float* __restrict__ Pp,
    float* __restrict__ h_in) {
  int blk = blockIdx.x;   // b*8 + rblk
  int b = blk >> 3;
  int r = ((blk & 7) << 8) + threadIdx.x;
  size_t o = ((size_t)b << 17) + r;          // b*NC*2048 + r
  float P0 = Pp[o], h0 = h_end[o];
  float H = 0.f;
  for (int c = 0; c < NC - 1; ++c) {
    size_t on = o + 2048;
    float Pn = Pp[on];                        // prefetch next chunk
    float hn_ = h_end[on];
    h_in[o] = H;
    H = fmaf(H, P0, h0);
    P0 = Pn; h0 = hn_; o = on;
  }
  h_in[o] = H;
}

// ---------------------------------------------------------------------------
// K56: final scan (waves 0-1) + concurrent out_proj weight staging (waves
// 2-3), then fused out-GEMM + residual + NCHW store. Block per (b, chunk).
// ysm/wsm swizzled: element t (or c) of row d lives at ((t + 4*(d&15))&63).
// ---------------------------------------------------------------------------
__global__ __launch_bounds__(256) void k56_scan_out(
    const float* __restrict__ dt_g, const float* __restrict__ Bm_g,
    const float* __restrict__ Cm_g, const float* __restrict__ xc_g,
    const float* __restrict__ A_log, const float* __restrict__ h_in,
    const float* __restrict__ z_g, const float* __restrict__ Dp,
    const float* __restrict__ opw, const float* __restrict__ seqT,
    float* __restrict__ out) {
  __shared__ __align__(16) float ysm[128 * 64];
  __shared__ __align__(16) float wsm[128 * 64];
  int tid = threadIdx.x;
  int blk = blockIdx.x;             // b*NC + ch
  int b = blk >> 6, ch = blk & 63;
  int l0 = ch << 6;
  if (tid < 128) {
    int d = tid;
    const float* dt_p = dt_g + ((size_t)b << 19);
    const float* xc_p = xc_g + ((size_t)b << 19);
    const float* z_p  = z_g  + ((size_t)b << 19);
    const float* Bm_p = Bm_g + ((size_t)b << 16);
    const float* Cm_p = Cm_g + ((size_t)b << 16);
    float A[16], h[16];
    const float* hi = h_in + ((((size_t)blk << 7) + d) << 4);
    #pragma unroll
    for (int q = 0; q < 4; ++q) {
      float4 a4 = *(const float4*)&A_log[d * 16 + q * 4];
      A[q*4]   = -__expf(a4.x); A[q*4+1] = -__expf(a4.y);
      A[q*4+2] = -__expf(a4.z); A[q*4+3] = -__expf(a4.w);
      float4 h4 = *(const float4*)&hi[q * 4];
      h[q*4] = h4.x; h[q*4+1] = h4.y; h[q*4+2] = h4.z; h[q*4+3] = h4.w;
    }
    float dpv = Dp[d];
    int sw = (d & 15) << 2;
    #pragma unroll 2
    for (int i = 0; i < CL; ++i) {
      int l = l0 + i;
      float dtv = dt_p[(l << 7) + d];
      float xcv = xc_p[(l << 7) + d];
      float dtx = dtv * xcv;
      float Bv[16], Cv[16];
      #pragma unroll
      for (int q = 0; q < 4; ++q) {
        float4 b4 = *(const float4*)&Bm_p[(l << 4) + q * 4];  // wave-uniform
        float4 c4 = *(const float4*)&Cm_p[(l << 4) + q * 4];  // wave-uniform
        Bv[q*4] = b4.x; Bv[q*4+1] = b4.y; Bv[q*4+2] = b4.z; Bv[q*4+3] = b4.w;
        Cv[q*4] = c4.x; Cv[q*4+1] = c4.y; Cv[q*4+2] = c4.z; Cv[q*4+3] = c4.w;
      }
      float y = 0.f;
      #pragma unroll
      for (int s = 0; s < 16; ++s) {
        float dA = __expf(dtv * A[s]);
        h[s] = fmaf(h[s], dA, dtx * Bv[s]);
        y = fmaf(h[s], Cv[s], y);
      }
      float zz = z_p[(l << 7) + d];
      float sil = zz / (1.f + __expf(-zz));
      ysm[(d << 6) + ((i + sw) & 63)] = (y + xcv * dpv) * sil;
    }
  } else {
    for (int i = tid - 128; i < 8192; i += 128) {
      int cc = i >> 7, d = i & 127;
      wsm[(d << 6) + ((cc + ((d & 15) << 2)) & 63)] = opw[i];
    }
  }
  __syncthreads();
  int t0 = (tid >> 4) << 2;
  int c0 = (tid & 15) << 2;
  float acc[4][4] = {};   // [t][c]
  #pragma unroll 4
  for (int d = 0; d < 128; ++d) {
    int sw = (d & 15) << 2;
    const float4 y4 = *(const float4*)&ysm[(d << 6) + ((t0 + sw) & 63)];
    const float4 w4 = *(const float4*)&wsm[(d << 6) + ((c0 + sw) & 63)];
    const float yv[4] = {y4.x, y4.y, y4.z, y4.w};
    const float wv[4] = {w4.x, w4.y, w4.z, w4.w};
    #pragma unroll
    for (int i = 0; i < 4; ++i)
      #pragma unroll
      for (int j = 0; j < 4; ++j)
        acc[i][j] = fmaf(yv[i], wv[j], acc[i][j]);
  }
  #pragma unroll
  for (int j = 0; j < 4; ++j) {
    size_t row = ((size_t)(b * 64 + c0 + j) << 12) + l0 + t0;
    float4 s4 = *(const float4*)&seqT[row];
    float4 o4 = make_float4(acc[0][j] + s4.x, acc[1][j] + s4.y,
                            acc[2][j] + s4.z, acc[3][j] + s4.w);
    *(float4*)&out[row] = o4;
  }
}

// ---------------------------------------------------------------------------
extern "C" void kernel_launch(void* const* d_in, const int* in_sizes, int n_in,
                              void* d_out, int out_size, void* d_ws, size_t ws_size,
                              hipStream_t stream) {
  const float* x       = (const float*)d_in[0];
  const float* dwh_w   = (const float*)d_in[1];
  const float* dwh_b   = (const float*)d_in[2];
  const float* dww_w   = (const float*)d_in[3];
  const float* dww_b   = (const float*)d_in[4];
  const float* conv_w  = (const float*)d_in[5];
  const float* conv_b  = (const float*)d_in[6];
  const float* bn_g    = (const float*)d_in[7];
  const float* bn_b    = (const float*)d_in[8];
  const float* bn_m    = (const float*)d_in[9];
  const float* bn_v    = (const float*)d_in[10];
  const float* ln_g    = (const float*)d_in[11];
  const float* ln_b    = (const float*)d_in[12];
  const float* ipw     = (const float*)d_in[13];
  const float* convd_w = (const float*)d_in[14];
  const float* convd_b = (const float*)d_in[15];
  const float* xpw     = (const float*)d_in[16];
  const float* dpw     = (const float*)d_in[17];
  const float* dpb     = (const float*)d_in[18];
  const float* A_log   = (const float*)d_in[19];
  const float* Dp      = (const float*)d_in[20];
  const float* opw     = (const float*)d_in[21];
  float* out = (float*)d_out;

  float* ws = (float*)d_ws;
  const size_t M = 1048576;  // 1M floats
  const size_t K = 262144;   // 256K floats
  // Liveness: hn dead after K3 -> h_end/P.  xm dead after K4 (unreused).
  float* seqT  = ws + 0;          // 1M  (K12 -> K56)
  float* hn    = ws + M;          // 1M  (K12 -> K3)
  float* h_end = ws + M;          // 512K (K5a -> K5b, hn region)
  float* P_buf = ws + M + 2 * K;  // 512K (K5a -> K5b)
  float* Bm    = ws + 2 * M;          // 256K (K4 -> K5a/K56)
  float* Cm    = ws + 2 * M + K;      // 256K
  float* h_in  = ws + 2 * M + 2 * K;  // 512K (K5b -> K56)
  float* xm    = ws + 3 * M;      // 2M  (K3 -> K4)
  float* z_buf = ws + 5 * M;      // 2M  (K3 -> K56)
  float* xc    = ws + 7 * M;      // 2M  (K4 -> K5a/K56)
  float* dt    = ws + 9 * M;      // 2M  (K4 -> K5a/K56)  => 44 MB total

  k12_front<<<256, 256, 0, stream>>>(x, dwh_w, dwh_b, dww_w, dww_b, conv_w,
                                     conv_b, bn_g, bn_b, bn_m, bn_v, ln_g,
                                     ln_b, seqT, hn);
  k3_inproj<<<dim3(256, 2), 256, 0, stream>>>(hn, ipw, xm, z_buf);
  k4_conv_proj<<<2048, 128, 0, stream>>>(xm, convd_w, convd_b, xpw, dpw, dpb,
                                         xc, dt, Bm, Cm);
  k5a_chunk<<<BB * NC, 128, 0, stream>>>(dt, Bm, xc, A_log, h_end, P_buf);
  k5b_carry<<<32, 256, 0, stream>>>(h_end, P_buf, h_in);
  k56_scan_out<<<BB * NC, 256, 0, stream>>>(dt, Bm, Cm, xc, A_log, h_in,
                                            z_buf, Dp, opw, seqT, out);
}